// Round 2
// baseline (356.723 us; speedup 1.0000x reference)
//
#include <hip/hip_runtime.h>
#include <math.h>

#define TWO_PI_F 6.28318530717958647692f
#define PI_F     3.14159265358979323846f

// One fused kernel:
//   blocks [0, res_blocks)            : resonance edge gathers (launched first:
//                                       latency-bound, overlaps with CE compute)
//   blocks [res_blocks, +ce_blocks)   : cross-entropy, one wave per row,
//                                       float4 loads + hw __expf/__logf
// Both paths atomicAdd pre-scaled contributions directly into out[0].
__global__ __launch_bounds__(256) void fused_kernel(
    const float* __restrict__ outputs,
    const int*   __restrict__ targets,
    const float* __restrict__ phase,
    const int*   __restrict__ esrc,
    const int*   __restrict__ edst,
    int B, int C, int N, int E,
    int res_blocks,
    float invB, float scaleE,
    float* __restrict__ out)
{
    const int lane = threadIdx.x & 63;

    if ((int)blockIdx.x < res_blocks) {
        // ---------------- resonance path: one thread per edge ----------------
        const int i = blockIdx.x * blockDim.x + threadIdx.x;
        float d = 0.0f;
        if (i < E) {
            const int s = esrc[i];
            const int t = edst[i];
            const float a = phase[(size_t)s * (size_t)N + (size_t)t];
            const float b = phase[(size_t)t * (size_t)N + (size_t)s];
            d = fabsf(a - b);
            d = fmodf(d, TWO_PI_F);
            if (d > PI_F) d = TWO_PI_F - d;
        }
        #pragma unroll
        for (int off = 32; off; off >>= 1)
            d += __shfl_xor(d, off, 64);
        if (lane == 0)
            atomicAdd(out, d * scaleE);
    } else {
        // ---------------- CE path: one wave per row --------------------------
        const int row = (blockIdx.x - res_blocks) * 4 + (threadIdx.x >> 6);
        if (row >= B) return;                      // wave-uniform exit

        const float*  rowp = outputs + (size_t)row * (size_t)C;
        const float4* row4 = (const float4*)rowp;
        const int nf4 = C >> 2;

        float4 v[4];
        int cnt = 0;
        for (int j = lane; j < nf4; j += 64)
            v[cnt++] = row4[j];

        // tail (C % 4 != 0) — not hit for C=1000 but kept for generality
        const int remBase = nf4 << 2;
        bool hasTail = (remBase + lane) < C;
        float tail = hasTail ? rowp[remBase + lane] : -INFINITY;

        float m = tail;
        for (int k = 0; k < cnt; k++)
            m = fmaxf(m, fmaxf(fmaxf(v[k].x, v[k].y), fmaxf(v[k].z, v[k].w)));
        #pragma unroll
        for (int off = 32; off; off >>= 1)
            m = fmaxf(m, __shfl_xor(m, off, 64));

        float s = 0.0f;
        for (int k = 0; k < cnt; k++)
            s += __expf(v[k].x - m) + __expf(v[k].y - m)
               + __expf(v[k].z - m) + __expf(v[k].w - m);
        if (hasTail) s += __expf(tail - m);
        #pragma unroll
        for (int off = 32; off; off >>= 1)
            s += __shfl_xor(s, off, 64);

        if (lane == 0) {
            const int t = targets[row];
            const float tv = rowp[t];              // row is hot in L1/L2
            atomicAdd(out, (m + __logf(s) - tv) * invB);
        }
    }
}

extern "C" void kernel_launch(void* const* d_in, const int* in_sizes, int n_in,
                              void* d_out, int out_size, void* d_ws, size_t ws_size,
                              hipStream_t stream) {
    const float* outputs = (const float*)d_in[0];
    const int*   targets = (const int*)d_in[1];
    const float* phase   = (const float*)d_in[2];
    const int*   esrc    = (const int*)d_in[3];
    const int*   edst    = (const int*)d_in[4];

    const int B = in_sizes[1];
    const int C = in_sizes[0] / B;
    const int E = in_sizes[3];
    int N = 1;
    while ((long long)N * (long long)N < (long long)in_sizes[2]) N++;

    float* out = (float*)d_out;
    hipMemsetAsync(out, 0, sizeof(float), stream);   // d_out re-poisoned each call

    const int res_blocks = (E + 255) / 256;          // 512
    const int ce_blocks  = (B + 3) / 4;              // 4096
    const int grid = res_blocks + ce_blocks;

    fused_kernel<<<grid, 256, 0, stream>>>(outputs, targets, phase, esrc, edst,
                                           B, C, N, E, res_blocks,
                                           1.0f / (float)B, 0.1f / (float)E,
                                           out);
}

// Round 3
// 184.113 us; speedup vs baseline: 1.9375x; 1.9375x over previous
//
#include <hip/hip_runtime.h>
#include <math.h>

#define TWO_PI_F 6.28318530717958647692f
#define PI_F     3.14159265358979323846f

// One fused kernel:
//   blocks [0, res_blocks)          : resonance edge gathers
//   blocks [res_blocks, +ce_blocks) : cross-entropy, one wave per row
// CE tile held in NAMED float4 registers (no arrays -> no LDS demotion).
// Per-block LDS reduction -> ONE atomic per block into out[0].
__global__ __launch_bounds__(256) void fused_kernel(
    const float* __restrict__ outputs,
    const int*   __restrict__ targets,
    const float* __restrict__ phase,
    const int*   __restrict__ esrc,
    const int*   __restrict__ edst,
    int B, int C, int N, int E,
    int res_blocks,
    float invB, float scaleE,
    float* __restrict__ out)
{
    __shared__ float part[4];
    const int lane = threadIdx.x & 63;
    const int wave = threadIdx.x >> 6;

    float wsum = 0.0f;                       // lane0-of-wave contribution (pre-scaled)

    if ((int)blockIdx.x < res_blocks) {
        // ---------------- resonance path: one thread per edge ----------------
        const int i = blockIdx.x * blockDim.x + threadIdx.x;
        float d = 0.0f;
        if (i < E) {
            const int s = esrc[i];
            const int t = edst[i];
            const float a = phase[(size_t)s * (size_t)N + (size_t)t];
            const float b = phase[(size_t)t * (size_t)N + (size_t)s];
            d = fabsf(a - b);
            d = fmodf(d, TWO_PI_F);
            if (d > PI_F) d = TWO_PI_F - d;
        }
        #pragma unroll
        for (int off = 32; off; off >>= 1)
            d += __shfl_xor(d, off, 64);
        if (lane == 0) wsum = d * scaleE;
    } else {
        // ---------------- CE path: one wave per row --------------------------
        const int row = (blockIdx.x - res_blocks) * 4 + wave;
        if (row < B) {
            const float*  rowp = outputs + (size_t)row * (size_t)C;
            const float4* row4 = (const float4*)rowp;
            const int nf4 = C >> 2;

            float m, s;
            if (nf4 <= 256) {
                // ---- fast path: whole row in 4 named float4 regs per lane ----
                const float4 NEG = make_float4(-INFINITY, -INFINITY, -INFINITY, -INFINITY);
                const int j0 = lane, j1 = lane + 64, j2 = lane + 128, j3 = lane + 192;
                float4 v0 = (j0 < nf4) ? row4[j0] : NEG;
                float4 v1 = (j1 < nf4) ? row4[j1] : NEG;
                float4 v2 = (j2 < nf4) ? row4[j2] : NEG;
                float4 v3 = (j3 < nf4) ? row4[j3] : NEG;
                const int remBase = nf4 << 2;
                const bool hasTail = (remBase + lane) < C;
                float tail = hasTail ? rowp[remBase + lane] : -INFINITY;

                m = tail;
                m = fmaxf(m, fmaxf(fmaxf(v0.x, v0.y), fmaxf(v0.z, v0.w)));
                m = fmaxf(m, fmaxf(fmaxf(v1.x, v1.y), fmaxf(v1.z, v1.w)));
                m = fmaxf(m, fmaxf(fmaxf(v2.x, v2.y), fmaxf(v2.z, v2.w)));
                m = fmaxf(m, fmaxf(fmaxf(v3.x, v3.y), fmaxf(v3.z, v3.w)));
                #pragma unroll
                for (int off = 32; off; off >>= 1)
                    m = fmaxf(m, __shfl_xor(m, off, 64));

                // __expf(-INF - m) == 0, so inactive slots contribute nothing
                s  = __expf(v0.x - m) + __expf(v0.y - m) + __expf(v0.z - m) + __expf(v0.w - m);
                s += __expf(v1.x - m) + __expf(v1.y - m) + __expf(v1.z - m) + __expf(v1.w - m);
                s += __expf(v2.x - m) + __expf(v2.y - m) + __expf(v2.z - m) + __expf(v2.w - m);
                s += __expf(v3.x - m) + __expf(v3.y - m) + __expf(v3.z - m) + __expf(v3.w - m);
                s += __expf(tail - m);
                #pragma unroll
                for (int off = 32; off; off >>= 1)
                    s += __shfl_xor(s, off, 64);
            } else {
                // ---- generic fallback: two passes, re-read global (L2-hot) ----
                m = -INFINITY;
                for (int j = lane; j < nf4; j += 64) {
                    float4 x = row4[j];
                    m = fmaxf(m, fmaxf(fmaxf(x.x, x.y), fmaxf(x.z, x.w)));
                }
                const int remBase = nf4 << 2;
                if (remBase + lane < C) m = fmaxf(m, rowp[remBase + lane]);
                #pragma unroll
                for (int off = 32; off; off >>= 1)
                    m = fmaxf(m, __shfl_xor(m, off, 64));

                s = 0.0f;
                for (int j = lane; j < nf4; j += 64) {
                    float4 x = row4[j];
                    s += __expf(x.x - m) + __expf(x.y - m)
                       + __expf(x.z - m) + __expf(x.w - m);
                }
                if (remBase + lane < C) s += __expf(rowp[remBase + lane] - m);
                #pragma unroll
                for (int off = 32; off; off >>= 1)
                    s += __shfl_xor(s, off, 64);
            }

            if (lane == 0) {
                const int t = targets[row];
                const float tv = rowp[t];          // row is hot in L1/L2
                wsum = (m + __logf(s) - tv) * invB;
            }
        }
    }

    if (lane == 0) part[wave] = wsum;
    __syncthreads();
    if (threadIdx.x == 0)
        atomicAdd(out, part[0] + part[1] + part[2] + part[3]);
}

extern "C" void kernel_launch(void* const* d_in, const int* in_sizes, int n_in,
                              void* d_out, int out_size, void* d_ws, size_t ws_size,
                              hipStream_t stream) {
    const float* outputs = (const float*)d_in[0];
    const int*   targets = (const int*)d_in[1];
    const float* phase   = (const float*)d_in[2];
    const int*   esrc    = (const int*)d_in[3];
    const int*   edst    = (const int*)d_in[4];

    const int B = in_sizes[1];
    const int C = in_sizes[0] / B;
    const int E = in_sizes[3];
    int N = 1;
    while ((long long)N * (long long)N < (long long)in_sizes[2]) N++;

    float* out = (float*)d_out;
    hipMemsetAsync(out, 0, sizeof(float), stream);

    const int res_blocks = (E + 255) / 256;          // 512
    const int ce_blocks  = (B + 3) / 4;              // 4096
    const int grid = res_blocks + ce_blocks;

    fused_kernel<<<grid, 256, 0, stream>>>(outputs, targets, phase, esrc, edst,
                                           B, C, N, E, res_blocks,
                                           1.0f / (float)B, 0.1f / (float)E,
                                           out);
}

// Round 4
// 148.405 us; speedup vs baseline: 2.4037x; 1.2406x over previous
//
#include <hip/hip_runtime.h>
#include <math.h>

#define TWO_PI_F 6.28318530717958647692f
#define PI_F     3.14159265358979323846f

// Stage 1: fused CE + resonance. Each block STORES one pre-scaled partial to
// ws[blockIdx] — no atomics (4608 same-address atomicAdds serialized ~15ns each
// = the entire 70us of R1/R3).
__global__ __launch_bounds__(256) void fused_kernel(
    const float* __restrict__ outputs,
    const int*   __restrict__ targets,
    const float* __restrict__ phase,
    const int*   __restrict__ esrc,
    const int*   __restrict__ edst,
    int B, int C, int N, int E,
    int res_blocks,
    float invB, float scaleE,
    float* __restrict__ ws)
{
    __shared__ float part[4];
    const int lane = threadIdx.x & 63;
    const int wave = threadIdx.x >> 6;

    float wsum = 0.0f;                       // lane0-of-wave contribution (pre-scaled)

    if ((int)blockIdx.x < res_blocks) {
        // ---------------- resonance path: one thread per edge ----------------
        const int i = blockIdx.x * blockDim.x + threadIdx.x;
        float d = 0.0f;
        if (i < E) {
            const int s = esrc[i];
            const int t = edst[i];
            const float a = phase[(size_t)s * (size_t)N + (size_t)t];
            const float b = phase[(size_t)t * (size_t)N + (size_t)s];
            d = fabsf(a - b);
            d = fmodf(d, TWO_PI_F);
            if (d > PI_F) d = TWO_PI_F - d;
        }
        #pragma unroll
        for (int off = 32; off; off >>= 1)
            d += __shfl_xor(d, off, 64);
        if (lane == 0) wsum = d * scaleE;
    } else {
        // ---------------- CE path: one wave per row --------------------------
        const int row = (blockIdx.x - res_blocks) * 4 + wave;
        if (row < B) {
            const float*  rowp = outputs + (size_t)row * (size_t)C;
            const float4* row4 = (const float4*)rowp;
            const int nf4 = C >> 2;

            float m, s;
            if (nf4 <= 256) {
                // ---- fast path: whole row in 4 named float4 regs per lane ----
                const float4 NEG = make_float4(-INFINITY, -INFINITY, -INFINITY, -INFINITY);
                const int j0 = lane, j1 = lane + 64, j2 = lane + 128, j3 = lane + 192;
                float4 v0 = (j0 < nf4) ? row4[j0] : NEG;
                float4 v1 = (j1 < nf4) ? row4[j1] : NEG;
                float4 v2 = (j2 < nf4) ? row4[j2] : NEG;
                float4 v3 = (j3 < nf4) ? row4[j3] : NEG;
                const int remBase = nf4 << 2;
                const bool hasTail = (remBase + lane) < C;
                float tail = hasTail ? rowp[remBase + lane] : -INFINITY;

                m = tail;
                m = fmaxf(m, fmaxf(fmaxf(v0.x, v0.y), fmaxf(v0.z, v0.w)));
                m = fmaxf(m, fmaxf(fmaxf(v1.x, v1.y), fmaxf(v1.z, v1.w)));
                m = fmaxf(m, fmaxf(fmaxf(v2.x, v2.y), fmaxf(v2.z, v2.w)));
                m = fmaxf(m, fmaxf(fmaxf(v3.x, v3.y), fmaxf(v3.z, v3.w)));
                #pragma unroll
                for (int off = 32; off; off >>= 1)
                    m = fmaxf(m, __shfl_xor(m, off, 64));

                // __expf(-INF - m) == 0, so inactive slots contribute nothing
                s  = __expf(v0.x - m) + __expf(v0.y - m) + __expf(v0.z - m) + __expf(v0.w - m);
                s += __expf(v1.x - m) + __expf(v1.y - m) + __expf(v1.z - m) + __expf(v1.w - m);
                s += __expf(v2.x - m) + __expf(v2.y - m) + __expf(v2.z - m) + __expf(v2.w - m);
                s += __expf(v3.x - m) + __expf(v3.y - m) + __expf(v3.z - m) + __expf(v3.w - m);
                s += __expf(tail - m);
                #pragma unroll
                for (int off = 32; off; off >>= 1)
                    s += __shfl_xor(s, off, 64);
            } else {
                // ---- generic fallback: two passes, re-read global (L2-hot) ----
                m = -INFINITY;
                for (int j = lane; j < nf4; j += 64) {
                    float4 x = row4[j];
                    m = fmaxf(m, fmaxf(fmaxf(x.x, x.y), fmaxf(x.z, x.w)));
                }
                const int remBase = nf4 << 2;
                if (remBase + lane < C) m = fmaxf(m, rowp[remBase + lane]);
                #pragma unroll
                for (int off = 32; off; off >>= 1)
                    m = fmaxf(m, __shfl_xor(m, off, 64));

                s = 0.0f;
                for (int j = lane; j < nf4; j += 64) {
                    float4 x = row4[j];
                    s += __expf(x.x - m) + __expf(x.y - m)
                       + __expf(x.z - m) + __expf(x.w - m);
                }
                if (remBase + lane < C) s += __expf(rowp[remBase + lane] - m);
                #pragma unroll
                for (int off = 32; off; off >>= 1)
                    s += __shfl_xor(s, off, 64);
            }

            if (lane == 0) {
                const int t = targets[row];
                const float tv = rowp[t];          // row is hot in L1/L2
                wsum = (m + __logf(s) - tv) * invB;
            }
        }
    }

    if (lane == 0) part[wave] = wsum;
    __syncthreads();
    if (threadIdx.x == 0)
        ws[blockIdx.x] = part[0] + part[1] + part[2] + part[3];   // plain store
}

// Stage 2: single block reduces all partials and writes the scalar output.
__global__ __launch_bounds__(256) void reduce_kernel(
    const float* __restrict__ ws, int P, float* __restrict__ out)
{
    float s = 0.0f;
    for (int i = threadIdx.x; i < P; i += 256)
        s += ws[i];
    #pragma unroll
    for (int off = 32; off; off >>= 1)
        s += __shfl_xor(s, off, 64);

    __shared__ float part[4];
    if ((threadIdx.x & 63) == 0) part[threadIdx.x >> 6] = s;
    __syncthreads();
    if (threadIdx.x == 0)
        out[0] = part[0] + part[1] + part[2] + part[3];
}

extern "C" void kernel_launch(void* const* d_in, const int* in_sizes, int n_in,
                              void* d_out, int out_size, void* d_ws, size_t ws_size,
                              hipStream_t stream) {
    const float* outputs = (const float*)d_in[0];
    const int*   targets = (const int*)d_in[1];
    const float* phase   = (const float*)d_in[2];
    const int*   esrc    = (const int*)d_in[3];
    const int*   edst    = (const int*)d_in[4];

    const int B = in_sizes[1];
    const int C = in_sizes[0] / B;
    const int E = in_sizes[3];
    int N = 1;
    while ((long long)N * (long long)N < (long long)in_sizes[2]) N++;

    const int res_blocks = (E + 255) / 256;          // 512
    const int ce_blocks  = (B + 3) / 4;              // 4096
    const int grid = res_blocks + ce_blocks;         // 4608 partials

    float* ws = (float*)d_ws;

    fused_kernel<<<grid, 256, 0, stream>>>(outputs, targets, phase, esrc, edst,
                                           B, C, N, E, res_blocks,
                                           1.0f / (float)B, 0.1f / (float)E,
                                           ws);
    reduce_kernel<<<1, 256, 0, stream>>>(ws, grid, (float*)d_out);
}